// Round 5
// baseline (439.077 us; speedup 1.0000x reference)
//
#include <hip/hip_runtime.h>

#define L_TOT   4096
#define CIN     32
#define G_L     4            // locations per block (same output row)
#define CH      4            // stages per chunk (stage s = c*3+ki, feature i = 3s+kj)
#define NCHUNK  24           // 96 stages total
#define CSF     (CH * 3 * 64)   // 768 floats = 3072 B per location per chunk
// LDS: xs 36864 B + wsm 2*12288 B = 61440 B -> 2 blocks/CU (122880 <= 163840)

// 16 FMAs: acc[bq][j] += PP.bq * WW.j  (param names must avoid x/y/z/w)
#define FMA16(PP, WW) {                                                        \
    acc[0][0] += PP.x * WW.x; acc[0][1] += PP.x * WW.y;                        \
    acc[0][2] += PP.x * WW.z; acc[0][3] += PP.x * WW.w;                        \
    acc[1][0] += PP.y * WW.x; acc[1][1] += PP.y * WW.y;                        \
    acc[1][2] += PP.y * WW.z; acc[1][3] += PP.y * WW.w;                        \
    acc[2][0] += PP.z * WW.x; acc[2][1] += PP.z * WW.y;                        \
    acc[2][2] += PP.z * WW.z; acc[2][3] += PP.z * WW.w;                        \
    acc[3][0] += PP.w * WW.x; acc[3][1] += PP.w * WW.y;                        \
    acc[3][2] += PP.w * WW.z; acc[3][3] += PP.w * WW.w; }

// compute one 4-stage chunk K out of LDS buffer BI (0/1)
#define COMPUTE4(K, BI) {                                                      \
    _Pragma("unroll")                                                          \
    for (int sl = 0; sl < CH; ++sl) {                                          \
        const int s = ((K) << 2) + sl;                                         \
        const float* pr = xs + ((6 * s + g) << 4) + (wv << 2);                 \
        float4 p0 = *(const float4*)(pr);                                      \
        float4 p1 = *(const float4*)(pr + 16);                                 \
        float4 p2 = *(const float4*)(pr + 32);                                 \
        const float4* wr = (const float4*)&wsm[BI][0] + g * 192 + sl * 48 + o4;\
        float4 w0 = wr[0];                                                     \
        float4 w1 = wr[16];                                                    \
        float4 w2 = wr[32];                                                    \
        FMA16(p0, w0); FMA16(p1, w1); FMA16(p2, w2);                           \
    } }

// issue chunk K's 3 pieces into reg slot SL (plain loads -> VGPR, deep flight)
#define ISSUE(SL, K) { _Pragma("unroll") for (int t = 0; t < 3; ++t)           \
    SL[t] = *(const float4*)(gsrc[t] + (size_t)(K) * CSF); }

// publish reg slot SL into LDS buffer BI (compiler inserts exact counted vmcnt
// before these ds_writes: 6 newer loads in flight in steady state)
#define PUBLISH(SL, BI) { _Pragma("unroll") for (int t = 0; t < 3; ++t)        \
    *(float4*)(&wsm[BI][ldsoff[t] + (lane << 2)]) = SL[t]; }

// raw barrier: drain only lgkm (our ds_reads/ds_writes), NEVER vmcnt ->
// the 2-3 chunks of global loads stay in flight across the barrier.
#define FENCE_BAR() { asm volatile("s_waitcnt lgkmcnt(0)" ::: "memory");       \
    __builtin_amdgcn_s_barrier(); }

// body J: issue(J+3) early -> compute(J) -> publish(J+1) late -> barrier
#define BODY(J, SISS, SPUB) { ISSUE(SISS, (J) + 3); COMPUTE4((J), (J) & 1);    \
    PUBLISH(SPUB, ((J) + 1) & 1); FENCE_BAR(); }

__global__ __launch_bounds__(256, 2)
void lc2d_v10(const float* __restrict__ x,
              const float* __restrict__ weight,
              const float* __restrict__ bias,
              float* __restrict__ out) {
    __shared__ __align__(16) float xs[576 * 16];     // [row=(c*3+dh)*6+wl][b]
    __shared__ __align__(16) float wsm[2][12 * 256]; // [buf][3072 floats]

    const int tid  = threadIdx.x;
    const int lane = tid & 63;
    const int wv   = tid >> 6;        // wave id -> b-quad base 4*wv
    const int g    = lane >> 4;       // location offset 0..3
    const int o4   = lane & 15;       // o-quad (o = 4*o4 .. 4*o4+3)

    // XCD-contiguous bijective remap: 1024 blocks = 8 XCDs * 128.
    const int bid  = blockIdx.x;
    const int swz  = ((bid & 7) << 7) | (bid >> 3);
    const int l0   = swz * G_L;
    const int oh   = l0 >> 6;
    const int ow0  = l0 & 63;

    // ---- per-wave piece setup: pieces p = wv, wv+4, wv+8 of each 12 KB chunk
    const float* gsrc[3];
    int ldsoff[3];
#pragma unroll
    for (int t = 0; t < 3; ++t) {
        int p   = wv + (t << 2);      // 0..11, wave-uniform
        int gg  = p / 3;
        int sub = p - 3 * gg;
        gsrc[t] = weight + (size_t)(l0 + gg) * (288 * 64) + sub * 256 + (lane << 2);
        ldsoff[t] = p * 256;          // float offset of piece base in wsm[buf]
    }

    // bias first: oldest in the vmcnt stream, so consuming it waits nothing else
    const float4 bias4 = ((const float4*)bias)[(l0 + g) * 16 + o4];

    // reg slots: chunk j lives in slot j%3 (A=0, B=1, C=2). Named, statically
    // indexed (rule #20: runtime-indexed reg arrays go to scratch).
    float4 sA[3], sB[3], sC[3];

    // ---- prologue: issue chunks 0,1,2 (9 loads in flight) ----
    ISSUE(sA, 0);
    ISSUE(sB, 1);
    ISSUE(sC, 2);

    // in-block coalesced x fill (as v9): 192 wave-tasks, lanes map to
    // (b-octet, consecutive w) -> ~8 L2-local lines/inst; hides under flight.
    {
        const int bq = lane >> 3;                 // 0..7
        const int w8 = lane & 7;                  // 0..7 (need 0..5)
        const int ww = ow0 - 1 + w8;              // -1..66
        const bool wok = (unsigned)ww < 64u;
        const int wwc = wok ? ww : 0;             // clamped
#pragma unroll 8
        for (int jj = 0; jj < 48; ++jj) {
            int task  = (jj << 2) + wv;           // 0..191, wave-uniform
            int bhalf = task & 1;
            int t     = task >> 1;                // c*3 + dh, 0..95
            int c     = t / 3;
            int dh    = t - 3 * c;
            int h     = oh - 1 + dh;
            bool hok  = (unsigned)h < 64u;
            int hc    = hok ? h : 0;              // clamped
            float v = x[((size_t)((bhalf << 3) + bq) << 17)
                        + (((c << 6) + hc) << 6) + wwc];
            v = (hok && wok) ? v : 0.0f;
            if (w8 < 6)
                xs[(t * 6 + w8) * 16 + (bhalf << 3) + bq] = v;
        }
    }

    float acc[4][4];
#pragma unroll
    for (int bq = 0; bq < 4; ++bq) {
        acc[bq][0] = bias4.x; acc[bq][1] = bias4.y;
        acc[bq][2] = bias4.z; acc[bq][3] = bias4.w;
    }

    // publish chunk 0 (auto-waits exactly until sA's loads land), then barrier
    PUBLISH(sA, 0);
    FENCE_BAR();

    // ---- main pipeline: 3 reg-chunks + 1 LDS chunk deep; loads never drained.
    // body j: issue(j+3)->slot j%3 | compute(j) from buf[j&1] |
    //         publish(j+1)->buf[(j+1)&1] (vmcnt(6) auto) | lgkm+barrier
    for (int j = 0; j <= 18; j += 3) {    // bodies 0..20, issues up to chunk 23
        BODY(j + 0, sA, sB);
        BODY(j + 1, sB, sC);
        BODY(j + 2, sC, sA);
    }
    // ---- tail: chunks 21,22,23 (slots A,B,C), no more issues
    COMPUTE4(21, 1); PUBLISH(sB, 0); FENCE_BAR();   // auto vmcnt(3)
    COMPUTE4(22, 0); PUBLISH(sC, 1); FENCE_BAR();   // auto vmcnt(0)
    COMPUTE4(23, 1);

    // ---- stores: out[((b*64 + o) << 12) + l0 + g], b = 4*wv+bq, o = 4*o4+j
#pragma unroll
    for (int bq = 0; bq < 4; ++bq) {
        const int b = (wv << 2) + bq;
#pragma unroll
        for (int j = 0; j < 4; ++j) {
            out[((size_t)((b << 6) + (o4 << 2) + j) << 12) + l0 + g] = acc[bq][j];
        }
    }
}

extern "C" void kernel_launch(void* const* d_in, const int* in_sizes, int n_in,
                              void* d_out, int out_size, void* d_ws, size_t ws_size,
                              hipStream_t stream) {
    const float* x      = (const float*)d_in[0];
    const float* weight = (const float*)d_in[1];
    const float* bias   = (const float*)d_in[2];
    float* out          = (float*)d_out;

    dim3 grid(L_TOT / G_L);   // 1024 blocks = 2 resident/CU
    dim3 block(256);
    hipLaunchKernelGGL(lc2d_v10, grid, block, 0, stream, x, weight, bias, out);
}

// Round 6
// 426.552 us; speedup vs baseline: 1.0294x; 1.0294x over previous
//
#include <hip/hip_runtime.h>

#define L_TOT   4096
#define CIN     32
#define G_L     4            // locations per block (same output row)
#define CH      4            // stages per chunk (stage s = c*3+ki, feature i = 3s+kj)
#define NCHUNK  24           // 96 stages total
#define CHUNK_STRIDE_F (CH * 3 * 64)   // 768 floats = 3072 B per location per chunk
// LDS: xs 36864 B + wsm 3*12288 B = 73728 B -> 2 blocks/CU (147456 <= 163840)

using f32g = __attribute__((address_space(1))) const float;
using f32l = __attribute__((address_space(3))) float;

// 16 FMAs: acc[bq][j] += PP.bq * WW.j  (param names must avoid x/y/z/w)
#define FMA16(PP, WW) {                                                        \
    acc[0][0] += PP.x * WW.x; acc[0][1] += PP.x * WW.y;                        \
    acc[0][2] += PP.x * WW.z; acc[0][3] += PP.x * WW.w;                        \
    acc[1][0] += PP.y * WW.x; acc[1][1] += PP.y * WW.y;                        \
    acc[1][2] += PP.y * WW.z; acc[1][3] += PP.y * WW.w;                        \
    acc[2][0] += PP.z * WW.x; acc[2][1] += PP.z * WW.y;                        \
    acc[2][2] += PP.z * WW.z; acc[2][3] += PP.z * WW.w;                        \
    acc[3][0] += PP.w * WW.x; acc[3][1] += PP.w * WW.y;                        \
    acc[3][2] += PP.w * WW.z; acc[3][3] += PP.w * WW.w; }

// compute one 4-stage chunk K out of LDS buffer at float-offset WOFF in wsm
#define COMPUTE4(K, WOFF) {                                                    \
    _Pragma("unroll")                                                          \
    for (int sl = 0; sl < CH; ++sl) {                                          \
        const int s = ((K) << 2) + sl;                                         \
        const float* pr = xs + ((6 * s + g) << 4) + (wv << 2);                 \
        float4 p0 = *(const float4*)(pr);                                      \
        float4 p1 = *(const float4*)(pr + 16);                                 \
        float4 p2 = *(const float4*)(pr + 32);                                 \
        const float4* wr = (const float4*)(&wsm[0][0] + (WOFF))                \
                           + g * 192 + sl * 48 + o4;                           \
        float4 w0 = wr[0];                                                     \
        float4 w1 = wr[16];                                                    \
        float4 w2 = wr[32];                                                    \
        FMA16(p0, w0); FMA16(p1, w1); FMA16(p2, w2);                           \
    } }

__global__ __launch_bounds__(256, 2)
void lc2d_v9(const float* __restrict__ x,
             const float* __restrict__ weight,
             const float* __restrict__ bias,
             float* __restrict__ out) {
    __shared__ __align__(16) float xs[576 * 16];     // [row=(c*3+dh)*6+wl][b]
    __shared__ __align__(16) float wsm[3][12 * 256]; // [buf][3072 floats = 12 KB]

    const int tid  = threadIdx.x;
    const int lane = tid & 63;
    const int wv   = tid >> 6;        // wave id -> b-quad base 4*wv
    const int g    = lane >> 4;       // location offset 0..3
    const int o4   = lane & 15;       // o-quad (o = 4*o4 .. 4*o4+3)

    // XCD-contiguous bijective remap: 1024 blocks = 8 XCDs * 128.
    // XCD x owns locations [x*512, x*512+512): 64B out lines (4 blocks) merge in
    // ONE L2; x-slab (10h x 32c x 16b x 256B = 1.31 MB) is L2-resident per XCD.
    const int bid  = blockIdx.x;
    const int swz  = ((bid & 7) << 7) | (bid >> 3);
    const int l0   = swz * G_L;
    const int oh   = l0 >> 6;
    const int ow0  = l0 & 63;

    // ---- per-wave DMA piece setup: pieces p = wv, wv+4, wv+8 of each 12 KB chunk
    const float* gsrc[3];
    int ldsoff[3];
#pragma unroll
    for (int t = 0; t < 3; ++t) {
        int p   = wv + (t << 2);      // 0..11, wave-uniform
        int gg  = p / 3;
        int sub = p - 3 * gg;
        gsrc[t] = weight + (size_t)(l0 + gg) * (288 * 64) + sub * 256 + (lane << 2);
        ldsoff[t] = p * 256;          // float offset of piece base in wsm[buf]
    }

    // ---- prologue: DMA chunks 0 AND 1 (2-deep) while filling the x tile ----
#pragma unroll
    for (int t = 0; t < 3; ++t)
        __builtin_amdgcn_global_load_lds((f32g*)(gsrc[t]),
                                         (f32l*)(&wsm[0][ldsoff[t]]), 16, 0, 0);
#pragma unroll
    for (int t = 0; t < 3; ++t)
        __builtin_amdgcn_global_load_lds((f32g*)(gsrc[t] + CHUNK_STRIDE_F),
                                         (f32l*)(&wsm[1][ldsoff[t]]), 16, 0, 0);

    // ---- in-block coalesced x fill. 192 wave-tasks: task = (j<<2)+wv.
    // lane -> (bq = lane>>3, w8 = lane&7); each inst touches 8 b-segments of
    // 8 consecutive w (~8 L2-local lines) vs 64 single-use lines in the old
    // b-strided gather. Clamp+select (no exec churn); hides under DMA flight.
    {
        const int bq = lane >> 3;                 // 0..7
        const int w8 = lane & 7;                  // 0..7 (need 0..5)
        const int ww = ow0 - 1 + w8;              // -1..66
        const bool wok = (unsigned)ww < 64u;
        const int wwc = wok ? ww : 0;             // clamped
#pragma unroll 8
        for (int j = 0; j < 48; ++j) {
            int task  = (j << 2) + wv;            // 0..191, wave-uniform
            int bhalf = task & 1;
            int t     = task >> 1;                // c*3 + dh, 0..95
            int c     = t / 3;                    // magic-mul
            int dh    = t - 3 * c;
            int h     = oh - 1 + dh;
            bool hok  = (unsigned)h < 64u;
            int hc    = hok ? h : 0;              // clamped
            float v = x[((size_t)((bhalf << 3) + bq) << 17)
                        + (((c << 6) + hc) << 6) + wwc];
            v = (hok && wok) ? v : 0.0f;
            if (w8 < 6)
                xs[(t * 6 + w8) * 16 + (bhalf << 3) + bq] = v;
        }
    }
    __syncthreads();   // full drain: DMA(0),DMA(1) + x fill resident for everyone

    const float4 bias4 = ((const float4*)bias)[(l0 + g) * 16 + o4];
    float acc[4][4];
#pragma unroll
    for (int bq = 0; bq < 4; ++bq) {
        acc[bq][0] = bias4.x; acc[bq][1] = bias4.y;
        acc[bq][2] = bias4.z; acc[bq][3] = bias4.w;
    }

    // ---- main pipeline: 3 buffers, 2 chunks in flight, never vmcnt(0).
    int wo0 = 0;              // holds chunk k
    int wo1 = 12 * 256;       // holds chunk k+1
    int wo2 = 2 * 12 * 256;   // DMA target for chunk k+2
    for (int k = 0; k < NCHUNK - 2; ++k) {
#pragma unroll
        for (int t = 0; t < 3; ++t)
            __builtin_amdgcn_global_load_lds(
                (f32g*)(gsrc[t] + (size_t)(k + 2) * CHUNK_STRIDE_F),
                (f32l*)(&wsm[0][0] + wo2 + ldsoff[t]), 16, 0, 0);
        COMPUTE4(k, wo0);
        asm volatile("s_waitcnt vmcnt(3) lgkmcnt(0)" ::: "memory");
        __builtin_amdgcn_s_barrier();
        asm volatile("" ::: "memory");
        int tmp = wo0; wo0 = wo1; wo1 = wo2; wo2 = tmp;
    }
    // tail: chunk 22 resident; drain DMA(23) fully, then finish
    COMPUTE4(NCHUNK - 2, wo0);
    asm volatile("s_waitcnt vmcnt(0) lgkmcnt(0)" ::: "memory");
    __builtin_amdgcn_s_barrier();
    asm volatile("" ::: "memory");
    COMPUTE4(NCHUNK - 1, wo1);

    // ---- stores: out[((b*64 + o) << 12) + l0 + g], b = 4*wv+bq, o = 4*o4+j
#pragma unroll
    for (int bq = 0; bq < 4; ++bq) {
        const int b = (wv << 2) + bq;
#pragma unroll
        for (int j = 0; j < 4; ++j) {
            out[((size_t)((b << 6) + (o4 << 2) + j) << 12) + l0 + g] = acc[bq][j];
        }
    }
}

extern "C" void kernel_launch(void* const* d_in, const int* in_sizes, int n_in,
                              void* d_out, int out_size, void* d_ws, size_t ws_size,
                              hipStream_t stream) {
    const float* x      = (const float*)d_in[0];
    const float* weight = (const float*)d_in[1];
    const float* bias   = (const float*)d_in[2];
    float* out          = (float*)d_out;

    dim3 grid(L_TOT / G_L);   // 1024 blocks = 2 resident/CU
    dim3 block(256);
    hipLaunchKernelGGL(lc2d_v9, grid, block, 0, stream, x, weight, bias, out);
}